// Round 1
// baseline (1467.912 us; speedup 1.0000x reference)
//
#include <hip/hip_runtime.h>
#include <hip/hip_bf16.h>

#define NN 50000
#define NE 1600000
#define HD 128
#define OD 128
#define NR 16

typedef __bf16 bf16x8 __attribute__((ext_vector_type(8)));
typedef unsigned short u16x8 __attribute__((ext_vector_type(8)));
typedef float f32x4 __attribute__((ext_vector_type(4)));

__device__ __forceinline__ unsigned short f2bf(float f) {
    union { float f; unsigned int u; } v; v.f = f;
    unsigned int u = v.u;
    u += 0x7FFFu + ((u >> 16) & 1u);   // round-to-nearest-even
    return (unsigned short)(u >> 16);
}
__device__ __forceinline__ float bflo(unsigned int u) {
    union { unsigned int u; float f; } v; v.u = u << 16; return v.f;
}
__device__ __forceinline__ float bfhi(unsigned int u) {
    union { unsigned int u; float f; } v; v.u = u & 0xFFFF0000u; return v.f;
}

// prep1: h_bf[n][k] = bf16(emb[node_ids[n]][k])
__global__ __launch_bounds__(256) void prep_h(const int* __restrict__ node_ids,
                                              const float* __restrict__ emb,
                                              unsigned short* __restrict__ h_bf) {
    int gid = blockIdx.x * 256 + threadIdx.x;
    if (gid >= NN * 32) return;
    int row = gid >> 5;
    int c = (gid & 31) << 2;
    int nid = node_ids[row];
    if (nid < 0) nid = 0; if (nid >= NN) nid = NN - 1;
    float4 v = *(const float4*)(emb + (size_t)nid * HD + c);
    ushort4 o;
    o.x = f2bf(v.x); o.y = f2bf(v.y); o.z = f2bf(v.z); o.w = f2bf(v.w);
    *(ushort4*)(h_bf + (size_t)row * HD + c) = o;
}

// prep2: Wt[r][o][k] = bf16(W[r][k][o])   (transposed so GEMM B-fragments are contiguous)
__global__ __launch_bounds__(256) void prep_w(const float* __restrict__ W,
                                              unsigned short* __restrict__ Wt) {
    int gid = blockIdx.x * 256 + threadIdx.x;
    if (gid >= NR * HD * OD) return;
    int r = gid >> 14;
    int idx = gid & 16383;
    int k = idx >> 7;
    int o = idx & 127;
    Wt[(size_t)r * 16384 + (size_t)o * 128 + k] = f2bf(W[gid]);
}

// GEMM: h_rel[r][n][o] = sum_k h_bf[n][k] * W[r][k][o], stored bf16.
// 128x128 node/out tile per block, 4 waves in 2x2, each wave 64x64 via 4x4
// grid of 16x16x32 bf16 MFMAs.
__global__ __launch_bounds__(256) void gemm_hrel(const unsigned short* __restrict__ h_bf,
                                                 const unsigned short* __restrict__ Wt,
                                                 unsigned short* __restrict__ h_rel) {
    __shared__ unsigned short sA[128][136];  // +8 pad: keeps 16B alignment, 2-way-max banks
    __shared__ unsigned short sB[128][136];
    const int t = threadIdx.x;
    const int tile = blockIdx.x;
    const int r = blockIdx.y;
    const int base = tile * 128;

    // stage A: 128 rows x 128 cols bf16, coalesced 16B chunks
    #pragma unroll
    for (int j = 0; j < 8; ++j) {
        int idx = t + j * 256;          // 0..2047
        int row = idx >> 4;             // 16 chunks of 8 elems per row
        int c8 = (idx & 15) << 3;
        int g = base + row;
        if (g >= NN) g = 0;             // clamp; values never stored
        uint4 v = *(const uint4*)(h_bf + (size_t)g * 128 + c8);
        *(uint4*)&sA[row][c8] = v;
    }
    // stage B: Wt[r] 128x128
    const unsigned short* wp = Wt + (size_t)r * 16384;
    #pragma unroll
    for (int j = 0; j < 8; ++j) {
        int idx = t + j * 256;
        int row = idx >> 4;
        int c8 = (idx & 15) << 3;
        uint4 v = *(const uint4*)(wp + (size_t)row * 128 + c8);
        *(uint4*)&sB[row][c8] = v;
    }
    __syncthreads();

    const int lane = t & 63;
    const int w = t >> 6;
    const int wr = w >> 1, wc = w & 1;
    const int l15 = lane & 15, lhi = lane >> 4;

    f32x4 acc[4][4];
    #pragma unroll
    for (int i = 0; i < 4; ++i)
        #pragma unroll
        for (int j = 0; j < 4; ++j)
            acc[i][j] = (f32x4){0.f, 0.f, 0.f, 0.f};

    #pragma unroll
    for (int kt = 0; kt < 4; ++kt) {
        const int ko = kt * 32 + lhi * 8;
        bf16x8 aF[4], bF[4];
        #pragma unroll
        for (int ms = 0; ms < 4; ++ms) {
            u16x8 raw = *(const u16x8*)&sA[wr * 64 + ms * 16 + l15][ko];
            aF[ms] = __builtin_bit_cast(bf16x8, raw);
        }
        #pragma unroll
        for (int nt = 0; nt < 4; ++nt) {
            u16x8 raw = *(const u16x8*)&sB[wc * 64 + nt * 16 + l15][ko];
            bF[nt] = __builtin_bit_cast(bf16x8, raw);
        }
        #pragma unroll
        for (int ms = 0; ms < 4; ++ms)
            #pragma unroll
            for (int nt = 0; nt < 4; ++nt)
                acc[ms][nt] = __builtin_amdgcn_mfma_f32_16x16x32_bf16(
                    aF[ms], bF[nt], acc[ms][nt], 0, 0, 0);
    }

    // epilogue: D layout col=lane&15, row=(lane>>4)*4+reg  [m89-verified]
    #pragma unroll
    for (int ms = 0; ms < 4; ++ms) {
        #pragma unroll
        for (int reg = 0; reg < 4; ++reg) {
            int m = base + wr * 64 + ms * 16 + lhi * 4 + reg;
            if (m < NN) {
                size_t rowp = ((size_t)r * NN + m) * 128;
                #pragma unroll
                for (int nt = 0; nt < 4; ++nt) {
                    int o = wc * 64 + nt * 16 + l15;
                    h_rel[rowp + o] = f2bf(acc[ms][nt][reg]);
                }
            }
        }
    }
}

// edge scatter: one wave per edge; lane handles 2 outputs (one dword of bf16x2)
__global__ __launch_bounds__(256) void edge_scatter(const int* __restrict__ src,
                                                    const int* __restrict__ dst,
                                                    const int* __restrict__ rel,
                                                    const float* __restrict__ norm,
                                                    const unsigned short* __restrict__ h_rel,
                                                    float* __restrict__ out) {
    int gid = blockIdx.x * 256 + threadIdx.x;
    int e = gid >> 6;
    if (e >= NE) return;
    int lane = gid & 63;
    int s = src[e], d = dst[e], r = rel[e];
    float nm = norm[e];
    const unsigned int* hp = (const unsigned int*)h_rel + ((size_t)r * NN + s) * 64 + lane;
    unsigned int u = *hp;
    float* op = out + (size_t)d * 128 + lane * 2;
    atomicAdd(op, bflo(u) * nm);
    atomicAdd(op + 1, bfhi(u) * nm);
}

extern "C" void kernel_launch(void* const* d_in, const int* in_sizes, int n_in,
                              void* d_out, int out_size, void* d_ws, size_t ws_size,
                              hipStream_t stream) {
    const int* node_ids = (const int*)d_in[0];
    const int* src      = (const int*)d_in[1];
    const int* dst      = (const int*)d_in[2];
    const int* rel      = (const int*)d_in[3];
    const float* norm   = (const float*)d_in[4];
    const float* emb    = (const float*)d_in[5];
    const float* W      = (const float*)d_in[6];
    float* out = (float*)d_out;

    char* ws = (char*)d_ws;
    unsigned short* h_rel = (unsigned short*)(ws);                        // 204,800,000 B
    unsigned short* h_bf  = (unsigned short*)(ws + 204800000);            //  12,800,000 B
    unsigned short* Wt    = (unsigned short*)(ws + 204800000 + 12800000); //     524,288 B

    hipMemsetAsync(d_out, 0, (size_t)out_size * sizeof(float), stream);
    prep_h<<<6250, 256, 0, stream>>>(node_ids, emb, h_bf);
    prep_w<<<(NR * HD * OD + 255) / 256, 256, 0, stream>>>(W, Wt);
    gemm_hrel<<<dim3(391, NR), 256, 0, stream>>>(h_bf, Wt, h_rel);
    edge_scatter<<<(NE * 64) / 256, 256, 0, stream>>>(src, dst, rel, norm, h_rel, out);
}

// Round 2
// 547.537 us; speedup vs baseline: 2.6809x; 2.6809x over previous
//
#include <hip/hip_runtime.h>
#include <hip/hip_bf16.h>

#define NN 50000
#define NE 1600000
#define HD 128
#define OD 128
#define NR 16

typedef __bf16 bf16x8 __attribute__((ext_vector_type(8)));
typedef unsigned short u16x8 __attribute__((ext_vector_type(8)));
typedef float f32x4 __attribute__((ext_vector_type(4)));

__device__ __forceinline__ unsigned short f2bf(float f) {
    union { float f; unsigned int u; } v; v.f = f;
    unsigned int u = v.u;
    u += 0x7FFFu + ((u >> 16) & 1u);   // round-to-nearest-even
    return (unsigned short)(u >> 16);
}
__device__ __forceinline__ float bflo(unsigned int u) {
    union { unsigned int u; float f; } v; v.u = u << 16; return v.f;
}
__device__ __forceinline__ float bfhi(unsigned int u) {
    union { unsigned int u; float f; } v; v.u = u & 0xFFFF0000u; return v.f;
}

// ---------------- phase 1: transform -------------------------------------

// prep1: h_bf[n][k] = bf16(emb[node_ids[n]][k])
__global__ __launch_bounds__(256) void prep_h(const int* __restrict__ node_ids,
                                              const float* __restrict__ emb,
                                              unsigned short* __restrict__ h_bf) {
    int gid = blockIdx.x * 256 + threadIdx.x;
    if (gid >= NN * 32) return;
    int row = gid >> 5;
    int c = (gid & 31) << 2;
    int nid = node_ids[row];
    if (nid < 0) nid = 0; if (nid >= NN) nid = NN - 1;
    float4 v = *(const float4*)(emb + (size_t)nid * HD + c);
    ushort4 o;
    o.x = f2bf(v.x); o.y = f2bf(v.y); o.z = f2bf(v.z); o.w = f2bf(v.w);
    *(ushort4*)(h_bf + (size_t)row * HD + c) = o;
}

// prep2: Wt[r][o][k] = bf16(W[r][k][o])
__global__ __launch_bounds__(256) void prep_w(const float* __restrict__ W,
                                              unsigned short* __restrict__ Wt) {
    int gid = blockIdx.x * 256 + threadIdx.x;
    if (gid >= NR * HD * OD) return;
    int r = gid >> 14;
    int idx = gid & 16383;
    int k = idx >> 7;
    int o = idx & 127;
    Wt[(size_t)r * 16384 + (size_t)o * 128 + k] = f2bf(W[gid]);
}

// GEMM: h_rel[r][n][o] = sum_k h_bf[n][k] * W[r][k][o], stored bf16.
__global__ __launch_bounds__(256) void gemm_hrel(const unsigned short* __restrict__ h_bf,
                                                 const unsigned short* __restrict__ Wt,
                                                 unsigned short* __restrict__ h_rel) {
    __shared__ unsigned short sA[128][136];
    __shared__ unsigned short sB[128][136];
    const int t = threadIdx.x;
    const int tile = blockIdx.x;
    const int r = blockIdx.y;
    const int base = tile * 128;

    #pragma unroll
    for (int j = 0; j < 8; ++j) {
        int idx = t + j * 256;
        int row = idx >> 4;
        int c8 = (idx & 15) << 3;
        int g = base + row;
        if (g >= NN) g = 0;
        uint4 v = *(const uint4*)(h_bf + (size_t)g * 128 + c8);
        *(uint4*)&sA[row][c8] = v;
    }
    const unsigned short* wp = Wt + (size_t)r * 16384;
    #pragma unroll
    for (int j = 0; j < 8; ++j) {
        int idx = t + j * 256;
        int row = idx >> 4;
        int c8 = (idx & 15) << 3;
        uint4 v = *(const uint4*)(wp + (size_t)row * 128 + c8);
        *(uint4*)&sB[row][c8] = v;
    }
    __syncthreads();

    const int lane = t & 63;
    const int w = t >> 6;
    const int wr = w >> 1, wc = w & 1;
    const int l15 = lane & 15, lhi = lane >> 4;

    f32x4 acc[4][4];
    #pragma unroll
    for (int i = 0; i < 4; ++i)
        #pragma unroll
        for (int j = 0; j < 4; ++j)
            acc[i][j] = (f32x4){0.f, 0.f, 0.f, 0.f};

    #pragma unroll
    for (int kt = 0; kt < 4; ++kt) {
        const int ko = kt * 32 + lhi * 8;
        bf16x8 aF[4], bF[4];
        #pragma unroll
        for (int ms = 0; ms < 4; ++ms) {
            u16x8 raw = *(const u16x8*)&sA[wr * 64 + ms * 16 + l15][ko];
            aF[ms] = __builtin_bit_cast(bf16x8, raw);
        }
        #pragma unroll
        for (int nt = 0; nt < 4; ++nt) {
            u16x8 raw = *(const u16x8*)&sB[wc * 64 + nt * 16 + l15][ko];
            bF[nt] = __builtin_bit_cast(bf16x8, raw);
        }
        #pragma unroll
        for (int ms = 0; ms < 4; ++ms)
            #pragma unroll
            for (int nt = 0; nt < 4; ++nt)
                acc[ms][nt] = __builtin_amdgcn_mfma_f32_16x16x32_bf16(
                    aF[ms], bF[nt], acc[ms][nt], 0, 0, 0);
    }

    #pragma unroll
    for (int ms = 0; ms < 4; ++ms) {
        #pragma unroll
        for (int reg = 0; reg < 4; ++reg) {
            int m = base + wr * 64 + ms * 16 + lhi * 4 + reg;
            if (m < NN) {
                size_t rowp = ((size_t)r * NN + m) * 128;
                #pragma unroll
                for (int nt = 0; nt < 4; ++nt) {
                    int o = wc * 64 + nt * 16 + l15;
                    h_rel[rowp + o] = f2bf(acc[ms][nt][reg]);
                }
            }
        }
    }
}

// ---------------- phase 2: counting sort by dst ---------------------------

__global__ __launch_bounds__(256) void hist_dst(const int* __restrict__ dst,
                                                int* __restrict__ counts) {
    int e = blockIdx.x * 256 + threadIdx.x;
    if (e >= NE) return;
    atomicAdd(&counts[dst[e]], 1);
}

// scanA: per-block (256 elems) sums -> blockSums[196]
__global__ __launch_bounds__(256) void scanA(const int* __restrict__ counts,
                                             int* __restrict__ blockSums) {
    __shared__ int s[256];
    int t = threadIdx.x;
    int idx = blockIdx.x * 256 + t;
    s[t] = (idx < NN) ? counts[idx] : 0;
    __syncthreads();
    for (int off = 128; off > 0; off >>= 1) {
        if (t < off) s[t] += s[t + off];
        __syncthreads();
    }
    if (t == 0) blockSums[blockIdx.x] = s[0];
}

// scanB: exclusive scan of 196 block sums (single block)
__global__ __launch_bounds__(256) void scanB(int* __restrict__ blockSums) {
    __shared__ int s[256];
    int t = threadIdx.x;
    int v = (t < 196) ? blockSums[t] : 0;
    s[t] = v;
    __syncthreads();
    for (int off = 1; off < 256; off <<= 1) {
        int x = (t >= off) ? s[t - off] : 0;
        __syncthreads();
        s[t] += x;
        __syncthreads();
    }
    if (t < 196) blockSums[t] = s[t] - v;   // exclusive
}

// scanC: per-block exclusive scan + block offset -> start[], cursor[]
__global__ __launch_bounds__(256) void scanC(const int* __restrict__ counts,
                                             const int* __restrict__ blockSums,
                                             int* __restrict__ start,
                                             int* __restrict__ cursor) {
    __shared__ int s[256];
    int t = threadIdx.x;
    int idx = blockIdx.x * 256 + t;
    int v = (idx < NN) ? counts[idx] : 0;
    s[t] = v;
    __syncthreads();
    for (int off = 1; off < 256; off <<= 1) {
        int x = (t >= off) ? s[t - off] : 0;
        __syncthreads();
        s[t] += x;
        __syncthreads();
    }
    if (idx < NN) {
        int excl = blockSums[blockIdx.x] + s[t] - v;
        start[idx] = excl;
        cursor[idx] = excl;
    }
    if (idx == 0) start[NN] = NE;
}

__global__ __launch_bounds__(256) void scatter_rank(const int* __restrict__ dst,
                                                    int* __restrict__ cursor,
                                                    int* __restrict__ sortedE) {
    int e = blockIdx.x * 256 + threadIdx.x;
    if (e >= NE) return;
    int pos = atomicAdd(&cursor[dst[e]], 1);
    sortedE[pos] = e;
}

// ---------------- phase 3: segmented reduction (no atomics) ---------------
// one wave per dst node; lane handles 2 output columns (one bf16x2 dword)
__global__ __launch_bounds__(256) void seg_reduce(const int* __restrict__ start,
                                                  const int* __restrict__ sortedE,
                                                  const int* __restrict__ src,
                                                  const int* __restrict__ rel,
                                                  const float* __restrict__ norm,
                                                  const unsigned short* __restrict__ h_rel,
                                                  float* __restrict__ out) {
    int gid = blockIdx.x * 256 + threadIdx.x;
    int d = gid >> 6;
    if (d >= NN) return;
    int lane = gid & 63;
    int beg = start[d], end = start[d + 1];
    const unsigned int* hb = (const unsigned int*)h_rel;
    float a0 = 0.f, a1 = 0.f;
    int i = beg;
    // unroll-by-2 with independent loads to let the compiler pipeline
    for (; i + 1 < end; i += 2) {
        int e0 = sortedE[i], e1 = sortedE[i + 1];
        int s0 = src[e0], r0 = rel[e0];
        int s1 = src[e1], r1 = rel[e1];
        float n0 = norm[e0], n1 = norm[e1];
        unsigned int u0 = hb[((size_t)r0 * NN + s0) * 64 + lane];
        unsigned int u1 = hb[((size_t)r1 * NN + s1) * 64 + lane];
        a0 += bflo(u0) * n0 + bflo(u1) * n1;
        a1 += bfhi(u0) * n0 + bfhi(u1) * n1;
    }
    if (i < end) {
        int e = sortedE[i];
        int s = src[e], r = rel[e];
        float nm = norm[e];
        unsigned int u = hb[((size_t)r * NN + s) * 64 + lane];
        a0 += bflo(u) * nm;
        a1 += bfhi(u) * nm;
    }
    *(float2*)(out + (size_t)d * 128 + lane * 2) = make_float2(a0, a1);
}

// ---------------- launch ---------------------------------------------------

extern "C" void kernel_launch(void* const* d_in, const int* in_sizes, int n_in,
                              void* d_out, int out_size, void* d_ws, size_t ws_size,
                              hipStream_t stream) {
    const int* node_ids = (const int*)d_in[0];
    const int* src      = (const int*)d_in[1];
    const int* dst      = (const int*)d_in[2];
    const int* rel      = (const int*)d_in[3];
    const float* norm   = (const float*)d_in[4];
    const float* emb    = (const float*)d_in[5];
    const float* W      = (const float*)d_in[6];
    float* out = (float*)d_out;

    char* ws = (char*)d_ws;
    unsigned short* h_rel = (unsigned short*)(ws);                 // 204,800,000 B
    unsigned short* h_bf  = (unsigned short*)(ws + 204800000);     //  12,800,000 B
    int* sortedE          = (int*)(ws + 204800000);                // ALIAS of h_bf (6.4 MB;
                                                                   // written only after gemm_hrel)
    unsigned short* Wt    = (unsigned short*)(ws + 217600000);     //     524,288 B
    int* counts           = (int*)(ws + 218124288);                //     200,704 B (50176 ints)
    int* start            = (int*)(ws + 218324992);                //     200,704 B (50001 ints)
    int* cursor           = (int*)(ws + 218525696);                //     200,704 B
    int* blockSums        = (int*)(ws + 218726400);                //       1,024 B

    hipMemsetAsync(counts, 0, 50176 * sizeof(int), stream);

    prep_h<<<6250, 256, 0, stream>>>(node_ids, emb, h_bf);
    prep_w<<<(NR * HD * OD + 255) / 256, 256, 0, stream>>>(W, Wt);
    hist_dst<<<(NE + 255) / 256, 256, 0, stream>>>(dst, counts);
    scanA<<<196, 256, 0, stream>>>(counts, blockSums);
    scanB<<<1, 256, 0, stream>>>(blockSums);
    scanC<<<196, 256, 0, stream>>>(counts, blockSums, start, cursor);

    gemm_hrel<<<dim3(391, NR), 256, 0, stream>>>(h_bf, Wt, h_rel);

    // sortedE aliases h_bf — must run after gemm_hrel (stream-serial: ok)
    scatter_rank<<<(NE + 255) / 256, 256, 0, stream>>>(dst, cursor, sortedE);

    seg_reduce<<<(NN * 64 + 255) / 256, 256, 0, stream>>>(start, sortedE, src, rel,
                                                          norm, h_rel, out);
}